// Round 1
// baseline (1484.543 us; speedup 1.0000x reference)
//
#include <hip/hip_runtime.h>
#include <hip/hip_bf16.h>
#include <stdint.h>

typedef __attribute__((ext_vector_type(8))) short short8;
typedef __attribute__((ext_vector_type(4))) float f32x4;
typedef unsigned long long ull;

__device__ __forceinline__ unsigned short f2bf(float f) {
  __hip_bfloat16 h = __float2bfloat16(f);
  return __builtin_bit_cast(unsigned short, h);
}
__device__ __forceinline__ float bf2f(uint32_t u) {
  return __builtin_bit_cast(float, u << 16);
}
__device__ __forceinline__ float sigf(float x) {
  return 1.0f / (1.0f + __expf(-x));
}
__device__ __forceinline__ float tanhfast(float x) {
  float t = fminf(fmaxf(x, -15.0f), 15.0f);
  float e = __expf(-2.0f * t);
  return (1.0f - e) / (1.0f + e);
}

__device__ __forceinline__ void gload_lds16(const __hip_bfloat16* g, __hip_bfloat16* lds) {
  __builtin_amdgcn_global_load_lds(
      (const __attribute__((address_space(1))) uint32_t*)g,
      (__attribute__((address_space(3))) uint32_t*)lds, 16, 0, 0);
}

// ---------------------------------------------------------------------------
// Kernel 0: convert ins -> bf16, build Wx^T bf16, zero counters
// ---------------------------------------------------------------------------
__global__ __launch_bounds__(256) void k_prep(
    const float* __restrict__ ins, const float* __restrict__ Wx,
    __hip_bfloat16* __restrict__ insb, __hip_bfloat16* __restrict__ wxt,
    uint32_t* __restrict__ counters) {
  const int tid = blockIdx.x * blockDim.x + threadIdx.x;
  const int nt = gridDim.x * blockDim.x;
  // ins: 33,554,432 f32 -> bf16 (as 8,388,608 float4)
  for (int i = tid; i < 8388608; i += nt) {
    float4 v = ((const float4*)ins)[i];
    ushort4 o;
    o.x = f2bf(v.x); o.y = f2bf(v.y); o.z = f2bf(v.z); o.w = f2bf(v.w);
    ((ushort4*)insb)[i] = o;
  }
  // WxT[c][k] = Wx[k][c]  (2048 x 512)
  for (int i = tid; i < 2048 * 512; i += nt) {
    const int c = i >> 9, k = i & 511;
    wxt[i] = __float2bfloat16(Wx[(size_t)k * 2048 + c]);
  }
  for (int i = tid; i < 16 * 256; i += nt) counters[i] = 0;
}

// ---------------------------------------------------------------------------
// Kernel 1: X = ins_bf16 @ Wx + b  (M=65536, K=512, N=2048), bf16 out
// m97-style 128x128 tile, BK=32, 4 waves (2x2), global_load_lds staging
// ---------------------------------------------------------------------------
__global__ __launch_bounds__(256) void k_gemm_x(
    const __hip_bfloat16* __restrict__ A,   // [65536][512]
    const __hip_bfloat16* __restrict__ BT,  // [2048][512]
    const float* __restrict__ bias,         // [2048]
    __hip_bfloat16* __restrict__ X) {       // [65536][2048]
  __shared__ __hip_bfloat16 As[128 * 32];
  __shared__ __hip_bfloat16 Bs[128 * 32];
  const int tid = threadIdx.x;
  const int w = tid >> 6, l = tid & 63;
  const int wr = w >> 1, wc = w & 1;
  const int mb = blockIdx.x >> 4, nb = blockIdx.x & 15;
  const int m0 = mb * 128, n0 = nb * 128;
  const int lrow = l >> 2;            // staging: 4 lanes per row
  const int lk = (l & 3) * 8;         // staging: 8 bf16 per lane
  const int fr = l & 15;              // fragment row/col
  const int fk = (l >> 4) * 8;        // fragment k offset

  f32x4 acc[4][4];
#pragma unroll
  for (int mi = 0; mi < 4; ++mi)
#pragma unroll
    for (int ni = 0; ni < 4; ++ni)
#pragma unroll
      for (int e = 0; e < 4; ++e) acc[mi][ni][e] = 0.0f;

  for (int kt = 0; kt < 16; ++kt) {
    const int k0 = kt * 32;
#pragma unroll
    for (int is = 0; is < 2; ++is) {
      const int ci = is * 4 + w;  // chunk 0..7: rows ci*16..+16
      gload_lds16(A + (size_t)(m0 + ci * 16 + lrow) * 512 + k0 + lk, As + ci * 512);
      gload_lds16(BT + (size_t)(n0 + ci * 16 + lrow) * 512 + k0 + lk, Bs + ci * 512);
    }
    __syncthreads();
    short8 af[4], bf[4];
#pragma unroll
    for (int mi = 0; mi < 4; ++mi)
      af[mi] = *(const short8*)(As + (wr * 64 + mi * 16 + fr) * 32 + fk);
#pragma unroll
    for (int ni = 0; ni < 4; ++ni)
      bf[ni] = *(const short8*)(Bs + (wc * 64 + ni * 16 + fr) * 32 + fk);
#pragma unroll
    for (int mi = 0; mi < 4; ++mi)
#pragma unroll
      for (int ni = 0; ni < 4; ++ni)
        acc[mi][ni] = __builtin_amdgcn_mfma_f32_16x16x32_bf16(af[mi], bf[ni], acc[mi][ni], 0, 0, 0);
    __syncthreads();
  }
  // epilogue: + bias, -> bf16. C/D layout: col=l&15, row=(l>>4)*4+reg
#pragma unroll
  for (int ni = 0; ni < 4; ++ni) {
    const int col = n0 + wc * 64 + ni * 16 + fr;
    const float bv = bias[col];
#pragma unroll
    for (int mi = 0; mi < 4; ++mi) {
      const int r0 = m0 + wr * 64 + mi * 16 + (l >> 4) * 4;
#pragma unroll
      for (int e = 0; e < 4; ++e)
        X[(size_t)(r0 + e) * 2048 + col] = __float2bfloat16(acc[mi][ni][e] + bv);
    }
  }
}

// ---------------------------------------------------------------------------
// Kernel 2: persistent recurrent scan.
// 256 blocks (1/CU): group g = bid&15 (16 batch rows), member = bid>>4
// (32 hidden outputs -> 128 Wh columns held in LDS for all 256 steps).
// Cross-block h exchange: relaxed AGENT atomics + per-(g,t) arrival counter.
// ---------------------------------------------------------------------------
__global__ __launch_bounds__(256, 1) void k_rec(
    const __hip_bfloat16* __restrict__ X,  // [T*B][2048]
    const int* __restrict__ resets,        // [T*B]
    const float* __restrict__ c0,          // [B][512]
    const float* __restrict__ h0,          // [B][512]
    const float* __restrict__ Wh,          // [512][2048]
    float* __restrict__ out,               // ys | cT | hT
    __hip_bfloat16* __restrict__ hist,     // [T*B][512]
    uint32_t* __restrict__ counters) {     // [16][256]
  __shared__ __hip_bfloat16 WhT[128][520];  // [local col][k], pad-> 2-way banks
  __shared__ __hip_bfloat16 hS[16][520];    // staged h tile
  __shared__ float zT[128][20];             // z transposed [col][row]
  __shared__ int rmaskS[16];

  const int tid = threadIdx.x;
  const int w = tid >> 6, l = tid & 63;
  const int g = blockIdx.x & 15, mem = blockIdx.x >> 4;
  const int b0 = g * 16, j0 = mem * 32;

  // ---- load Wh slice -> WhT (local col c: gate=c>>5, q=c&31) ----
  {
    const int c = tid & 127;
    const int gcol = (c >> 5) * 512 + j0 + (c & 31);
    for (int kb = (tid >> 7) * 4; kb < 512; kb += 8) {
      ushort4 pk;
      pk.x = f2bf(Wh[(size_t)(kb + 0) * 2048 + gcol]);
      pk.y = f2bf(Wh[(size_t)(kb + 1) * 2048 + gcol]);
      pk.z = f2bf(Wh[(size_t)(kb + 2) * 2048 + gcol]);
      pk.w = f2bf(Wh[(size_t)(kb + 3) * 2048 + gcol]);
      *(ushort4*)&WhT[c][kb] = pk;
    }
  }

  const int r_ = tid >> 4;        // 0..15: batch row within tile (stage + gates)
  const int q2 = (tid & 15) * 2;  // gates: first of 2 hidden cols
  const int schunk = tid & 15;    // staging: 32-elem chunk within row
  float creg0 = c0[(size_t)(b0 + r_) * 512 + j0 + q2];
  float creg1 = c0[(size_t)(b0 + r_) * 512 + j0 + q2 + 1];
  float hlast0 = 0.f, hlast1 = 0.f;
  uint32_t* myctr = counters + g * 256;

  __syncthreads();

  for (int t = 0; t < 256; ++t) {
    if (t > 0) {
      if (tid == 0) {
        while (__hip_atomic_load(&myctr[t - 1], __ATOMIC_RELAXED,
                                 __HIP_MEMORY_SCOPE_AGENT) < 16u)
          __builtin_amdgcn_s_sleep(8);
      }
      __syncthreads();
    }
    // ---- stage h_{t-1} (reset-masked) into hS ----
    const int rst = resets[t * 256 + b0 + r_];
    if (schunk == 0) rmaskS[r_] = rst;
    if (t == 0) {
      const float* hp = h0 + (size_t)(b0 + r_) * 512 + schunk * 32;
#pragma unroll
      for (int jj = 0; jj < 8; ++jj) {
        float4 v = ((const float4*)hp)[jj];
        ushort4 pk;
        pk.x = f2bf(v.x); pk.y = f2bf(v.y); pk.z = f2bf(v.z); pk.w = f2bf(v.w);
        if (rst) { pk.x = 0; pk.y = 0; pk.z = 0; pk.w = 0; }
        *(ushort4*)&hS[r_][schunk * 32 + jj * 4] = pk;
      }
    } else {
      ull* hp = (ull*)(hist + (size_t)((t - 1) * 256 + b0 + r_) * 512 + schunk * 32);
#pragma unroll
      for (int jj = 0; jj < 8; ++jj) {
        ull v = __hip_atomic_load(hp + jj, __ATOMIC_RELAXED, __HIP_MEMORY_SCOPE_AGENT);
        if (rst) v = 0;
        *(ull*)&hS[r_][schunk * 32 + jj * 4] = v;
      }
    }
    __syncthreads();

    // ---- GEMM: z[16 x 128] = hS @ WhT^T; wave w owns cols w*32..+32 ----
    f32x4 a0, a1;
#pragma unroll
    for (int e = 0; e < 4; ++e) { a0[e] = 0.f; a1[e] = 0.f; }
    const int fr = l & 15, fk = (l >> 4) * 8;
#pragma unroll
    for (int ks = 0; ks < 16; ++ks) {
      short8 af = *(const short8*)&hS[fr][ks * 32 + fk];
      short8 bf0 = *(const short8*)&WhT[w * 32 + fr][ks * 32 + fk];
      short8 bf1 = *(const short8*)&WhT[w * 32 + 16 + fr][ks * 32 + fk];
      a0 = __builtin_amdgcn_mfma_f32_16x16x32_bf16(af, bf0, a0, 0, 0, 0);
      a1 = __builtin_amdgcn_mfma_f32_16x16x32_bf16(af, bf1, a1, 0, 0, 0);
    }
    const int zr = (l >> 4) * 4;  // C/D: col=l&15, row=(l>>4)*4+reg
    *(f32x4*)&zT[w * 32 + fr][zr] = a0;
    *(f32x4*)&zT[w * 32 + 16 + fr][zr] = a1;
    __syncthreads();

    // ---- gates: thread handles (r_, q2) and (r_, q2+1) ----
    const int rst2 = rmaskS[r_];
    const size_t xbase = ((size_t)t * 256 + b0 + r_) * 2048 + j0 + q2;
    const uint32_t xi = *(const uint32_t*)(X + xbase);
    const uint32_t xf = *(const uint32_t*)(X + xbase + 512);
    const uint32_t xg = *(const uint32_t*)(X + xbase + 1024);
    const uint32_t xo = *(const uint32_t*)(X + xbase + 1536);
    const float zi0 = zT[q2][r_]      + bf2f(xi & 0xffffu);
    const float zi1 = zT[q2 + 1][r_]  + bf2f(xi >> 16);
    const float zf0 = zT[32 + q2][r_] + bf2f(xf & 0xffffu);
    const float zf1 = zT[33 + q2][r_] + bf2f(xf >> 16);
    const float zg0 = zT[64 + q2][r_] + bf2f(xg & 0xffffu);
    const float zg1 = zT[65 + q2][r_] + bf2f(xg >> 16);
    const float zo0 = zT[96 + q2][r_] + bf2f(xo & 0xffffu);
    const float zo1 = zT[97 + q2][r_] + bf2f(xo >> 16);
    const float cp0 = rst2 ? 0.f : creg0;
    const float cp1 = rst2 ? 0.f : creg1;
    creg0 = sigf(zf0) * cp0 + sigf(zi0) * tanhfast(zg0);
    creg1 = sigf(zf1) * cp1 + sigf(zi1) * tanhfast(zg1);
    hlast0 = sigf(zo0) * tanhfast(creg0);
    hlast1 = sigf(zo1) * tanhfast(creg1);

    const size_t ybase = ((size_t)t * 256 + b0 + r_) * 512 + j0 + q2;
    float2 yv; yv.x = hlast0; yv.y = hlast1;
    *(float2*)(out + ybase) = yv;
    const uint32_t hw = ((uint32_t)f2bf(hlast1) << 16) | (uint32_t)f2bf(hlast0);
    __hip_atomic_store((uint32_t*)(hist + ybase), hw, __ATOMIC_RELAXED,
                       __HIP_MEMORY_SCOPE_AGENT);
    // __syncthreads drains vmcnt(0) for every wave -> all stores at coherence
    // point before the arrival counter bump (hand-rolled release, no wbl2).
    __syncthreads();
    if (tid == 0)
      __hip_atomic_fetch_add(&myctr[t], 1u, __ATOMIC_RELAXED, __HIP_MEMORY_SCOPE_AGENT);
  }

  // ---- finals: cT, hT ----
  const size_t cbase = (size_t)33554432 + (size_t)(b0 + r_) * 512 + j0 + q2;
  out[cbase] = creg0;
  out[cbase + 1] = creg1;
  out[cbase + 131072] = hlast0;
  out[cbase + 131072 + 1] = hlast1;
}

// ---------------------------------------------------------------------------
extern "C" void kernel_launch(void* const* d_in, const int* in_sizes, int n_in,
                              void* d_out, int out_size, void* d_ws, size_t ws_size,
                              hipStream_t stream) {
  const float* ins    = (const float*)d_in[0];
  const int*   resets = (const int*)d_in[1];
  const float* c0     = (const float*)d_in[2];
  const float* h0     = (const float*)d_in[3];
  const float* Wx     = (const float*)d_in[4];
  const float* Wh     = (const float*)d_in[5];
  const float* bias   = (const float*)d_in[6];
  float* out = (float*)d_out;
  char* ws = (char*)d_ws;

  __hip_bfloat16* insb = (__hip_bfloat16*)ws;                      // 67,108,864 B
  __hip_bfloat16* wxt  = (__hip_bfloat16*)(ws + 67108864);         //  2,097,152 B
  __hip_bfloat16* Xb   = (__hip_bfloat16*)(ws + 69206016);         // 268,435,456 B
  __hip_bfloat16* hist = (__hip_bfloat16*)(ws + 337641472);        // 67,108,864 B
  uint32_t*       ctr  = (uint32_t*)(ws + 404750336);              //     16,384 B

  k_prep<<<2048, 256, 0, stream>>>(ins, Wx, insb, wxt, ctr);
  k_gemm_x<<<8192, 256, 0, stream>>>(insb, wxt, bias, Xb);
  k_rec<<<256, 256, 0, stream>>>(Xb, resets, c0, h0, Wh, out, hist, ctr);
}

// Round 3
// 1457.060 us; speedup vs baseline: 1.0189x; 1.0189x over previous
//
#include <hip/hip_runtime.h>
#include <hip/hip_bf16.h>
#include <stdint.h>

typedef __attribute__((ext_vector_type(8))) short short8;
typedef __attribute__((ext_vector_type(4))) float f32x4;

__device__ __forceinline__ unsigned short f2bf(float f) {
  __hip_bfloat16 h = __float2bfloat16(f);
  return __builtin_bit_cast(unsigned short, h);
}
__device__ __forceinline__ float bf2f(uint32_t u) {
  return __builtin_bit_cast(float, u << 16);
}
__device__ __forceinline__ float sigf(float x) {
  return 1.0f / (1.0f + __expf(-x));
}
__device__ __forceinline__ float tanhfast(float x) {
  float t = fminf(fmaxf(x, -15.0f), 15.0f);
  float e = __expf(-2.0f * t);
  return (1.0f - e) / (1.0f + e);
}

__device__ __forceinline__ void gload_lds16(const __hip_bfloat16* g, __hip_bfloat16* lds) {
  __builtin_amdgcn_global_load_lds(
      (const __attribute__((address_space(1))) uint32_t*)g,
      (__attribute__((address_space(3))) uint32_t*)lds, 16, 0, 0);
}

// ---------------------------------------------------------------------------
// Kernel 0: ins->bf16, Wx^T bf16, h0->bf16 (hist slot 0), zero flags+zeropage
// ---------------------------------------------------------------------------
__global__ __launch_bounds__(256) void k_prep(
    const float* __restrict__ ins, const float* __restrict__ Wx,
    const float* __restrict__ h0,
    __hip_bfloat16* __restrict__ insb, __hip_bfloat16* __restrict__ wxt,
    __hip_bfloat16* __restrict__ hist0, uint32_t* __restrict__ ctr) {
  const int tid = blockIdx.x * blockDim.x + threadIdx.x;
  const int nt = gridDim.x * blockDim.x;
  for (int i = tid; i < 8388608; i += nt) {          // ins (33.5M f32)
    float4 v = ((const float4*)ins)[i];
    ushort4 o;
    o.x = f2bf(v.x); o.y = f2bf(v.y); o.z = f2bf(v.z); o.w = f2bf(v.w);
    ((ushort4*)insb)[i] = o;
  }
  for (int i = tid; i < 2048 * 512; i += nt) {       // WxT[c][k] = Wx[k][c]
    const int c = i >> 9, k = i & 511;
    wxt[i] = __float2bfloat16(Wx[(size_t)k * 2048 + c]);
  }
  for (int i = tid; i < 32768; i += nt) {            // h0 -> hist slot 0
    float4 v = ((const float4*)h0)[i];
    ushort4 o;
    o.x = f2bf(v.x); o.y = f2bf(v.y); o.z = f2bf(v.z); o.w = f2bf(v.w);
    ((ushort4*)hist0)[i] = o;
  }
  for (int i = tid; i < 4096; i += nt) ctr[i] = 0;   // flags[256] + zeros page
}

// ---------------------------------------------------------------------------
// Kernel 1: X = insb @ Wx + b  (M=65536, K=512, N=2048), bf16 out (unchanged)
// ---------------------------------------------------------------------------
__global__ __launch_bounds__(256) void k_gemm_x(
    const __hip_bfloat16* __restrict__ A,
    const __hip_bfloat16* __restrict__ BT,
    const float* __restrict__ bias,
    __hip_bfloat16* __restrict__ X) {
  __shared__ __hip_bfloat16 As[128 * 32];
  __shared__ __hip_bfloat16 Bs[128 * 32];
  const int tid = threadIdx.x;
  const int w = tid >> 6, l = tid & 63;
  const int wr = w >> 1, wc = w & 1;
  const int mb = blockIdx.x >> 4, nb = blockIdx.x & 15;
  const int m0 = mb * 128, n0 = nb * 128;
  const int lrow = l >> 2;
  const int lk = (l & 3) * 8;
  const int fr = l & 15;
  const int fk = (l >> 4) * 8;

  f32x4 acc[4][4];
#pragma unroll
  for (int mi = 0; mi < 4; ++mi)
#pragma unroll
    for (int ni = 0; ni < 4; ++ni)
#pragma unroll
      for (int e = 0; e < 4; ++e) acc[mi][ni][e] = 0.0f;

  for (int kt = 0; kt < 16; ++kt) {
    const int k0 = kt * 32;
#pragma unroll
    for (int is = 0; is < 2; ++is) {
      const int ci = is * 4 + w;
      gload_lds16(A + (size_t)(m0 + ci * 16 + lrow) * 512 + k0 + lk, As + ci * 512);
      gload_lds16(BT + (size_t)(n0 + ci * 16 + lrow) * 512 + k0 + lk, Bs + ci * 512);
    }
    __syncthreads();
    short8 af[4], bf[4];
#pragma unroll
    for (int mi = 0; mi < 4; ++mi)
      af[mi] = *(const short8*)(As + (wr * 64 + mi * 16 + fr) * 32 + fk);
#pragma unroll
    for (int ni = 0; ni < 4; ++ni)
      bf[ni] = *(const short8*)(Bs + (wc * 64 + ni * 16 + fr) * 32 + fk);
#pragma unroll
    for (int mi = 0; mi < 4; ++mi)
#pragma unroll
      for (int ni = 0; ni < 4; ++ni)
        acc[mi][ni] = __builtin_amdgcn_mfma_f32_16x16x32_bf16(af[mi], bf[ni], acc[mi][ni], 0, 0, 0);
    __syncthreads();
  }
#pragma unroll
  for (int ni = 0; ni < 4; ++ni) {
    const int col = n0 + wc * 64 + ni * 16 + fr;
    const float bv = bias[col];
#pragma unroll
    for (int mi = 0; mi < 4; ++mi) {
      const int r0 = m0 + wr * 64 + mi * 16 + (l >> 4) * 4;
#pragma unroll
      for (int e = 0; e < 4; ++e)
        X[(size_t)(r0 + e) * 2048 + col] = __float2bfloat16(acc[mi][ni][e] + bv);
    }
  }
}

// ---------------------------------------------------------------------------
// Kernel 2: persistent recurrent scan, register-resident Wh.
// 256 blocks (1/CU). group g=bid&15 (16 batch rows), member=bid>>4 (32 cols).
// hist slot t holds h_{t-1} (bf16); slot 0 pre-filled by k_prep.
// Release: stores -> s_waitcnt vmcnt(0) -> prefetch -> raw s_barrier -> flag.
// Acquire: ballot-poll per-member flags (relaxed agent), asm dep pins A-loads.
// ---------------------------------------------------------------------------
__global__ __launch_bounds__(256, 1) void k_rec(
    const __hip_bfloat16* __restrict__ X,   // [T*256][2048]
    const int* __restrict__ resets,         // [T*256]
    const float* __restrict__ c0,           // [256][512]
    const float* __restrict__ Wh,           // [512][2048] f32
    float* __restrict__ out,                // ys | cT | hT
    __hip_bfloat16* __restrict__ hist,      // [257*256][512]
    uint32_t* __restrict__ ctr) {
  __shared__ float zT[128][20];             // z transposed [local col][row]

  const int tid = threadIdx.x;
  const int w = tid >> 6, l = tid & 63;
  const int g = blockIdx.x & 15, mem = blockIdx.x >> 4;
  const int b0 = g * 16, j0 = mem * 32;
  const int fr = l & 15, fk = (l >> 4) * 8;
  const int r_ = tid >> 4, q2 = (tid & 15) * 2;

  uint32_t* flags = ctr;                            // [16 groups][16 members]
  const char* zpage = (const char*)ctr + 4096;      // 4KB of zeros
  const char* histc = (const char*)hist;

  // ---- one-time: B fragments (Wh f32 -> bf16), held in VGPRs all 256 steps.
  // wave w = gate w; tile0 -> hidden cols j0+fr, tile1 -> j0+16+fr.
  short8 bfr[2][16];
#pragma unroll
  for (int tile = 0; tile < 2; ++tile) {
    const int gcol = w * 512 + j0 + tile * 16 + fr;
#pragma unroll
    for (int ks = 0; ks < 16; ++ks) {
      short8 v;
#pragma unroll
      for (int j = 0; j < 8; ++j)
        v[j] = (short)f2bf(Wh[(size_t)(ks * 32 + fk + j) * 2048 + gcol]);
      bfr[tile][ks] = v;
    }
  }

  float creg0 = c0[(size_t)(b0 + r_) * 512 + j0 + q2];
  float creg1 = c0[(size_t)(b0 + r_) * 512 + j0 + q2 + 1];
  float hl0 = 0.f, hl1 = 0.f;

  // prefetch step 0 inputs
  int rv = resets[b0 + fr];
  size_t xb = (size_t)(b0 + r_) * 2048 + j0 + q2;
  uint32_t xi = *(const uint32_t*)(X + xb);
  uint32_t xf_ = *(const uint32_t*)(X + xb + 512);
  uint32_t xg = *(const uint32_t*)(X + xb + 1024);
  uint32_t xo = *(const uint32_t*)(X + xb + 1536);

  for (int t = 0; t < 256; ++t) {
    uint32_t hoff = ((uint32_t)(t * 256 + b0 + fr) * 512u + (uint32_t)fk) * 2u;
    if (t > 0) {
      const uint32_t want = (uint32_t)t;
      const int fidx = g * 16 + fr;
      uint32_t v = __hip_atomic_load(&flags[fidx], __ATOMIC_RELAXED,
                                     __HIP_MEMORY_SCOPE_AGENT);
      while (__ballot(v < want) != 0ull) {
        __builtin_amdgcn_s_sleep(1);
        v = __hip_atomic_load(&flags[fidx], __ATOMIC_RELAXED,
                              __HIP_MEMORY_SCOPE_AGENT);
      }
      asm volatile("" : "+v"(hoff) : "v"(v));  // pin A-loads after flag observe
    }
    // A fragments straight from global (write-once-read-once per slot;
    // reset rows redirected to the zeros page)
    const char* ap = rv ? zpage : (histc + hoff);
    short8 af[16];
#pragma unroll
    for (int ks = 0; ks < 16; ++ks)
      af[ks] = *(const short8*)(ap + ks * 64);

    f32x4 a0, a1;
#pragma unroll
    for (int e = 0; e < 4; ++e) { a0[e] = 0.f; a1[e] = 0.f; }
#pragma unroll
    for (int ks = 0; ks < 16; ++ks) {
      a0 = __builtin_amdgcn_mfma_f32_16x16x32_bf16(af[ks], bfr[0][ks], a0, 0, 0, 0);
      a1 = __builtin_amdgcn_mfma_f32_16x16x32_bf16(af[ks], bfr[1][ks], a1, 0, 0, 0);
    }
    const int zr = (l >> 4) * 4;  // C/D: col=l&15, row=(l>>4)*4+e
    *(f32x4*)&zT[w * 32 + fr][zr] = a0;
    *(f32x4*)&zT[w * 32 + 16 + fr][zr] = a1;
    const int rstr = __shfl(rv, r_, 64);  // reset flag for this gate row
    __syncthreads();

    // gates: thread = (r_, q2..q2+1); local col = gate*32 + q
    const float zi0 = zT[q2][r_]      + bf2f(xi & 0xffffu);
    const float zi1 = zT[q2 + 1][r_]  + bf2f(xi >> 16);
    const float zf0 = zT[32 + q2][r_] + bf2f(xf_ & 0xffffu);
    const float zf1 = zT[33 + q2][r_] + bf2f(xf_ >> 16);
    const float zg0 = zT[64 + q2][r_] + bf2f(xg & 0xffffu);
    const float zg1 = zT[65 + q2][r_] + bf2f(xg >> 16);
    const float zo0 = zT[96 + q2][r_] + bf2f(xo & 0xffffu);
    const float zo1 = zT[97 + q2][r_] + bf2f(xo >> 16);
    const float cp0 = rstr ? 0.f : creg0;
    const float cp1 = rstr ? 0.f : creg1;
    creg0 = sigf(zf0) * cp0 + sigf(zi0) * tanhfast(zg0);
    creg1 = sigf(zf1) * cp1 + sigf(zi1) * tanhfast(zg1);
    hl0 = sigf(zo0) * tanhfast(creg0);
    hl1 = sigf(zo1) * tanhfast(creg1);

    const size_t ybase = ((size_t)t * 256 + b0 + r_) * 512 + j0 + q2;
    float2 yv; yv.x = hl0; yv.y = hl1;
    *(float2*)(out + ybase) = yv;
    const uint32_t hw = ((uint32_t)f2bf(hl1) << 16) | (uint32_t)f2bf(hl0);
    __hip_atomic_store((uint32_t*)(hist + ybase + 131072), hw, __ATOMIC_RELAXED,
                       __HIP_MEMORY_SCOPE_AGENT);  // slot t+1

    // drain ONLY the stores (prefetch not yet issued), then prefetch t+1,
    // then raw barrier (no auto-drain) and publish.
    asm volatile("s_waitcnt vmcnt(0)" ::: "memory");
    const int tn = (t < 255) ? (t + 1) : 255;
    rv = resets[tn * 256 + b0 + fr];
    xb = ((size_t)tn * 256 + b0 + r_) * 2048 + j0 + q2;
    xi = *(const uint32_t*)(X + xb);
    xf_ = *(const uint32_t*)(X + xb + 512);
    xg = *(const uint32_t*)(X + xb + 1024);
    xo = *(const uint32_t*)(X + xb + 1536);
    asm volatile("" ::: "memory");
    __builtin_amdgcn_s_barrier();
    asm volatile("" ::: "memory");
    if (tid == 0)
      __hip_atomic_store(&flags[g * 16 + mem], (uint32_t)(t + 1),
                         __ATOMIC_RELAXED, __HIP_MEMORY_SCOPE_AGENT);
  }

  // finals: cT, hT
  const size_t cbase = (size_t)33554432 + (size_t)(b0 + r_) * 512 + j0 + q2;
  out[cbase] = creg0;
  out[cbase + 1] = creg1;
  out[cbase + 131072] = hl0;
  out[cbase + 131072 + 1] = hl1;
}

// ---------------------------------------------------------------------------
extern "C" void kernel_launch(void* const* d_in, const int* in_sizes, int n_in,
                              void* d_out, int out_size, void* d_ws, size_t ws_size,
                              hipStream_t stream) {
  const float* ins    = (const float*)d_in[0];
  const int*   resets = (const int*)d_in[1];
  const float* c0     = (const float*)d_in[2];
  const float* h0     = (const float*)d_in[3];
  const float* Wx     = (const float*)d_in[4];
  const float* Wh     = (const float*)d_in[5];
  const float* bias   = (const float*)d_in[6];
  float* out = (float*)d_out;
  char* ws = (char*)d_ws;

  // layout (bytes):
  __hip_bfloat16* hist = (__hip_bfloat16*)ws;                      // 67,371,008 (257 slots)
  __hip_bfloat16* insb = (__hip_bfloat16*)(ws + 67371008);         // 67,108,864
  __hip_bfloat16* wxt  = (__hip_bfloat16*)(ws + 134479872);        //  2,097,152
  __hip_bfloat16* Xb   = (__hip_bfloat16*)(ws + 136577024);        // 268,435,456
  uint32_t*       ctr  = (uint32_t*)(ws + 405012480);              //     16,384

  k_prep<<<2048, 256, 0, stream>>>(ins, Wx, h0, insb, wxt, hist, ctr);
  k_gemm_x<<<8192, 256, 0, stream>>>(insb, wxt, bias, Xb);
  k_rec<<<256, 256, 0, stream>>>(Xb, resets, c0, Wh, out, hist, ctr);
}